// Round 1
// baseline (207.778 us; speedup 1.0000x reference)
//
#include <hip/hip_runtime.h>

// CMOW word-matrix chain product.
// sent:  [1024, 64] int32 indices
// table: [30001, 784] fp32 (row = flattened 28x28 matrix, row-major)
// out:   [1024, 784] fp32 = prod_{i=0..63} M_{sent[b,i]} (left-to-right)
//
// One block (256 thr = 4 waves) per batch row. Each wave computes the product
// of its 16-matrix chunk (15 sequential 28^3 matmuls), then a 2-level tree
// combines the 4 chunk products. 49 lanes/wave hold 4x4 register tiles;
// cur is col-major in LDS (A-side b128 reads), M row-major (B-side b128 reads).
// Next M is register-prefetched from global during compute.

#define MD    28
#define MD2   784
#define SEQL  64
#define CHUNK 16

__global__ __launch_bounds__(256, 4)
void cmow_chain_kernel(const int* __restrict__ sent,
                       const float* __restrict__ table,
                       float* __restrict__ out)
{
    // per wave: [bufA(784) | bufB(784) | mrow(784)]  -> 4*3*784 floats = 37632 B
    __shared__ float lds[4 * 3 * MD2];

    const int tid  = threadIdx.x;
    const int w    = tid >> 6;     // wave id 0..3
    const int lane = tid & 63;
    const int b    = blockIdx.x;

    float* bufA = &lds[(w * 3 + 0) * MD2];
    float* bufB = &lds[(w * 3 + 1) * MD2];
    float* mrow = &lds[(w * 3 + 2) * MD2];

    const int* srow = sent + b * SEQL;
    const int  base = w * CHUNK;

    // ---- load first matrix of this wave's chunk, transposed -> col-major bufA
    {
        const float* m0 = table + (size_t)srow[base] * MD2;
        for (int e = lane; e < MD2; e += 64) {
            const int r = e / MD, c = e % MD;
            bufA[c * MD + r] = m0[e];
        }
    }

    // ---- prefetch M_{base+1} into registers (196 float4 per matrix)
    float4 pf0, pf1, pf2, pf3 = make_float4(0.f, 0.f, 0.f, 0.f);
    {
        const float4* m4 = (const float4*)(table + (size_t)srow[base + 1] * MD2);
        pf0 = m4[lane];
        pf1 = m4[lane + 64];
        pf2 = m4[lane + 128];
        if (lane < 4) pf3 = m4[lane + 192];
    }

    const int  r0     = (lane / 7) * 4;
    const int  c0     = (lane % 7) * 4;
    const bool active = (lane < 49);

    float* src = bufA;
    float* dst = bufB;

    for (int i = 1; i < CHUNK; ++i) {
        // commit prefetched matrix to LDS, row-major
        {
            float4* m4w = (float4*)mrow;
            m4w[lane]       = pf0;
            m4w[lane + 64]  = pf1;
            m4w[lane + 128] = pf2;
            if (lane < 4) m4w[lane + 192] = pf3;
        }
        __syncthreads();

        // prefetch next matrix while computing this one
        if (i + 1 < CHUNK) {
            const float4* m4 = (const float4*)(table + (size_t)srow[base + i + 1] * MD2);
            pf0 = m4[lane];
            pf1 = m4[lane + 64];
            pf2 = m4[lane + 128];
            if (lane < 4) pf3 = m4[lane + 192];
        }

        if (active) {
            float acc[4][4];
            #pragma unroll
            for (int ri = 0; ri < 4; ++ri)
                #pragma unroll
                for (int ci = 0; ci < 4; ++ci) acc[ri][ci] = 0.f;

            #pragma unroll
            for (int k = 0; k < MD; ++k) {
                const float4 a  = *(const float4*)(src  + k * MD + r0);  // cur[r0..r0+3][k]
                const float4 bb = *(const float4*)(mrow + k * MD + c0);  // M[k][c0..c0+3]
                acc[0][0] += a.x * bb.x; acc[0][1] += a.x * bb.y; acc[0][2] += a.x * bb.z; acc[0][3] += a.x * bb.w;
                acc[1][0] += a.y * bb.x; acc[1][1] += a.y * bb.y; acc[1][2] += a.y * bb.z; acc[1][3] += a.y * bb.w;
                acc[2][0] += a.z * bb.x; acc[2][1] += a.z * bb.y; acc[2][2] += a.z * bb.z; acc[2][3] += a.z * bb.w;
                acc[3][0] += a.w * bb.x; acc[3][1] += a.w * bb.y; acc[3][2] += a.w * bb.z; acc[3][3] += a.w * bb.w;
            }

            // write new cur, col-major
            #pragma unroll
            for (int ci = 0; ci < 4; ++ci) {
                float4 col;
                col.x = acc[0][ci]; col.y = acc[1][ci]; col.z = acc[2][ci]; col.w = acc[3][ci];
                *(float4*)(dst + (c0 + ci) * MD + r0) = col;
            }
        }
        __syncthreads();
        float* t = src; src = dst; dst = t;
    }

    // ---- phase 2: combine the 4 chunk products (all stored col-major)
    const int srcSel = (CHUNK - 1) & 1;   // buffer index holding P_w after the loop
    #define PBUF(wv, sel) (&lds[((wv) * 3 + (sel)) * MD2])

    // step 1: wave0: P01 = P0 @ P1 ; wave1: P23 = P2 @ P3
    if (w < 2 && active) {
        const float* A = PBUF(2 * w,     srcSel);   // col-major
        const float* B = PBUF(2 * w + 1, srcSel);   // col-major (strided reads)
        float acc[4][4];
        #pragma unroll
        for (int ri = 0; ri < 4; ++ri)
            #pragma unroll
            for (int ci = 0; ci < 4; ++ci) acc[ri][ci] = 0.f;

        #pragma unroll
        for (int k = 0; k < MD; ++k) {
            const float4 a  = *(const float4*)(A + k * MD + r0);
            const float  b0 = B[(c0 + 0) * MD + k];
            const float  b1 = B[(c0 + 1) * MD + k];
            const float  b2 = B[(c0 + 2) * MD + k];
            const float  b3 = B[(c0 + 3) * MD + k];
            acc[0][0] += a.x * b0; acc[0][1] += a.x * b1; acc[0][2] += a.x * b2; acc[0][3] += a.x * b3;
            acc[1][0] += a.y * b0; acc[1][1] += a.y * b1; acc[1][2] += a.y * b2; acc[1][3] += a.y * b3;
            acc[2][0] += a.z * b0; acc[2][1] += a.z * b1; acc[2][2] += a.z * b2; acc[2][3] += a.z * b3;
            acc[3][0] += a.w * b0; acc[3][1] += a.w * b1; acc[3][2] += a.w * b2; acc[3][3] += a.w * b3;
        }
        float* D = PBUF(w, srcSel ^ 1);
        #pragma unroll
        for (int ci = 0; ci < 4; ++ci) {
            float4 col;
            col.x = acc[0][ci]; col.y = acc[1][ci]; col.z = acc[2][ci]; col.w = acc[3][ci];
            *(float4*)(D + (c0 + ci) * MD + r0) = col;
        }
    }
    __syncthreads();

    // step 2: final = P01 @ P23 -> global out (row-major)
    if (w == 0 && active) {
        const float* A = PBUF(0, srcSel ^ 1);
        const float* B = PBUF(1, srcSel ^ 1);
        float acc[4][4];
        #pragma unroll
        for (int ri = 0; ri < 4; ++ri)
            #pragma unroll
            for (int ci = 0; ci < 4; ++ci) acc[ri][ci] = 0.f;

        #pragma unroll
        for (int k = 0; k < MD; ++k) {
            const float4 a  = *(const float4*)(A + k * MD + r0);
            const float  b0 = B[(c0 + 0) * MD + k];
            const float  b1 = B[(c0 + 1) * MD + k];
            const float  b2 = B[(c0 + 2) * MD + k];
            const float  b3 = B[(c0 + 3) * MD + k];
            acc[0][0] += a.x * b0; acc[0][1] += a.x * b1; acc[0][2] += a.x * b2; acc[0][3] += a.x * b3;
            acc[1][0] += a.y * b0; acc[1][1] += a.y * b1; acc[1][2] += a.y * b2; acc[1][3] += a.y * b3;
            acc[2][0] += a.z * b0; acc[2][1] += a.z * b1; acc[2][2] += a.z * b2; acc[2][3] += a.z * b3;
            acc[3][0] += a.w * b0; acc[3][1] += a.w * b1; acc[3][2] += a.w * b2; acc[3][3] += a.w * b3;
        }
        float* op = out + (size_t)b * MD2;
        #pragma unroll
        for (int ri = 0; ri < 4; ++ri) {
            float4 row;
            row.x = acc[ri][0]; row.y = acc[ri][1]; row.z = acc[ri][2]; row.w = acc[ri][3];
            *(float4*)(op + (r0 + ri) * MD + c0) = row;
        }
    }
    #undef PBUF
}

extern "C" void kernel_launch(void* const* d_in, const int* in_sizes, int n_in,
                              void* d_out, int out_size, void* d_ws, size_t ws_size,
                              hipStream_t stream) {
    const int*   sent  = (const int*)d_in[0];
    const float* table = (const float*)d_in[1];
    float*       outp  = (float*)d_out;

    const int batch = in_sizes[0] / SEQL;   // 1024
    cmow_chain_kernel<<<dim3(batch), dim3(256), 0, stream>>>(sent, table, outp);
}